// Round 1
// baseline (425.754 us; speedup 1.0000x reference)
//
#include <hip/hip_runtime.h>

// SlotElmanCell: T=1024, Bb=2, D=1024, S=64
//   decay = sigmoid(decay_logits)            [D,S]
//   h[t+1] = decay*h[t] + B*x[t]             [Bb,D,S]
//   out[t] = (h[t+1] . C) * silu(z[t])       [Bb,D]
// Outputs (concat flat): out [T,Bb,D] then h [T+1,Bb,D,S]  (f32)

#define T_  1024
#define BB_ 2
#define D_  1024
#define S_  64

__global__ __launch_bounds__(256, 2) void slot_elman_kernel(
    const float* __restrict__ x, const float* __restrict__ z,
    const float* __restrict__ h0, const float* __restrict__ dl,
    const float* __restrict__ Bm, const float* __restrict__ C,
    float* __restrict__ out, float* __restrict__ h)
{
    // Bijective XCD-aware block swizzle: 512 blocks, 8 XCDs, 64 blocks/XCD.
    // Blocks resident on the same XCD get consecutive d-chunks -> x/z cache
    // lines (16 consecutive d per 64B line) stay in one L2.
    const int nb  = gridDim.x;            // 512
    const int cpx = nb >> 3;              // 64
    const int bid = blockIdx.x;
    const int swz = (bid & 7) * cpx + (bid >> 3);

    const int wave = swz * (blockDim.x >> 6) + (threadIdx.x >> 6); // 0..2047
    const int lane = threadIdx.x & 63;                             // slot s
    const int b  = wave >> 10;            // D_=1024
    const int d  = wave & (D_ - 1);
    const int bd = b * D_ + d;
    const int ds = d * S_ + lane;

    // Per-lane constants
    const float decay = 1.0f / (1.0f + __expf(-dl[ds]));
    const float Bv    = Bm[ds];
    const float Cv    = C[lane];

    // Initial state + h[0] write
    float hv = h0[(size_t)bd * S_ + lane];
    h[(size_t)bd * S_ + lane] = hv;

    const float* xp = x + bd;                                   // stride Bb*D
    const float* zp = z + bd;
    float*       hp = h + (size_t)(BB_ * D_ * S_) + (size_t)bd * S_ + lane;
    float*       op = out + bd;

    // Prefetch t=0 (wave-uniform scalars)
    float xv = xp[0];
    float zv = zp[0];

    #pragma unroll 4
    for (int t = 0; t < T_; ++t) {
        // Prefetch next step's x/z so the load latency hides under this
        // step's reduce+store (recurrence chain is only the FMA below).
        const int tn = (t + 1 < T_) ? (t + 1) : (T_ - 1);
        const float xn = xp[(size_t)tn * (BB_ * D_)];
        const float zn = zp[(size_t)tn * (BB_ * D_)];

        // State update (the only loop-carried dependency)
        hv = fmaf(decay, hv, Bv * xv);

        // Coalesced h write: 64 lanes x 4B contiguous
        hp[(size_t)t * (BB_ * D_ * S_)] = hv;

        // out[t] = (sum_s h*C) * silu(z)  -- 6-step butterfly over 64 lanes
        float p = hv * Cv;
        #pragma unroll
        for (int m = 32; m; m >>= 1) p += __shfl_xor(p, m, 64);
        if (lane == 0) {
            const float sg = 1.0f / (1.0f + __expf(-zv));
            op[(size_t)t * (BB_ * D_)] = p * (zv * sg);
        }

        xv = xn; zv = zn;
    }
}

extern "C" void kernel_launch(void* const* d_in, const int* in_sizes, int n_in,
                              void* d_out, int out_size, void* d_ws, size_t ws_size,
                              hipStream_t stream) {
    const float* x  = (const float*)d_in[0];   // [T,Bb,D]
    const float* z  = (const float*)d_in[1];   // [T,Bb,D]
    const float* h0 = (const float*)d_in[2];   // [Bb,D,S]
    const float* dl = (const float*)d_in[3];   // [D,S]
    const float* Bm = (const float*)d_in[4];   // [D,S]
    const float* C  = (const float*)d_in[5];   // [S]

    float* out = (float*)d_out;                            // [T,Bb,D]
    float* h   = (float*)d_out + (size_t)T_ * BB_ * D_;    // [T+1,Bb,D,S]

    const int waves  = BB_ * D_;          // 2048
    const int block  = 256;               // 4 waves
    const int grid   = waves * 64 / block; // 512

    hipLaunchKernelGGL(slot_elman_kernel, dim3(grid), dim3(block), 0, stream,
                       x, z, h0, dl, Bm, C, out, h);
}

// Round 2
// 406.410 us; speedup vs baseline: 1.0476x; 1.0476x over previous
//
#include <hip/hip_runtime.h>

// SlotElmanCell: T=1024, Bb=2, D=1024, S=64
//   decay = sigmoid(decay_logits)            [D,S]
//   h[t+1] = decay*h[t] + B*x[t]             [Bb,D,S]
//   out[t] = (h[t+1] . C) * silu(z[t])       [Bb,D]
// Outputs (concat flat): out [T,Bb,D] then h [T+1,Bb,D,S]  (f32)
//
// R2: replace __shfl_xor butterfly (6 x ~120cy DS-pipe latency per step)
// with DPP VALU reduction (6 x ~4cy, no LDS): row_shr 1/2/4/8 then
// row_bcast:15 (rows 1,3) + row_bcast:31 (rows 2,3). Sum lands in lane 63.

#define T_  1024
#define BB_ 2
#define D_  1024
#define S_  64

// x + dpp_shifted(x); bound_ctrl=1 -> out-of-range sources read 0,
// masked-out lanes get old (=0) so the add is a no-op there.
#define DPP_ADD(x, ctrl, rm) \
  ((x) + __int_as_float(__builtin_amdgcn_update_dpp( \
        0, __float_as_int(x), (ctrl), (rm), 0xf, true)))

__global__ __launch_bounds__(256, 2) void slot_elman_kernel(
    const float* __restrict__ x, const float* __restrict__ z,
    const float* __restrict__ h0, const float* __restrict__ dl,
    const float* __restrict__ Bm, const float* __restrict__ C,
    float* __restrict__ out, float* __restrict__ h)
{
    // Bijective XCD-aware block swizzle: 512 blocks, 8 XCDs, 64 blocks/XCD.
    const int nb  = gridDim.x;            // 512
    const int cpx = nb >> 3;              // 64
    const int bid = blockIdx.x;
    const int swz = (bid & 7) * cpx + (bid >> 3);

    const int wave = swz * (blockDim.x >> 6) + (threadIdx.x >> 6); // 0..2047
    const int lane = threadIdx.x & 63;                             // slot s
    const int b  = wave >> 10;            // D_=1024
    const int d  = wave & (D_ - 1);
    const int bd = b * D_ + d;
    const int ds = d * S_ + lane;

    // Per-lane constants
    const float decay = 1.0f / (1.0f + __expf(-dl[ds]));
    const float Bv    = Bm[ds];
    const float Cv    = C[lane];

    // Initial state + h[0] write
    float hv = h0[(size_t)bd * S_ + lane];
    h[(size_t)bd * S_ + lane] = hv;

    const float* xp = x + bd;                                   // stride Bb*D
    const float* zp = z + bd;
    float*       hp = h + (size_t)(BB_ * D_ * S_) + (size_t)bd * S_ + lane;
    float*       op = out + bd;

    // Prefetch t=0 (wave-uniform scalars)
    float xv = xp[0];
    float zv = zp[0];

    #pragma unroll 4
    for (int t = 0; t < T_; ++t) {
        // Prefetch next step's x/z (address-independent -> compiler can
        // hoist several iterations ahead under the unroll).
        const int tn = (t + 1 < T_) ? (t + 1) : (T_ - 1);
        const float xn = xp[(size_t)tn * (BB_ * D_)];
        const float zn = zp[(size_t)tn * (BB_ * D_)];

        // State update (the only loop-carried dependency, ~4 cycles)
        hv = fmaf(decay, hv, Bv * xv);

        // Coalesced h write: 64 lanes x 4B contiguous
        hp[(size_t)t * (BB_ * D_ * S_)] = hv;

        // Wave-wide sum of hv*Cv via DPP (pure VALU, no LDS).
        float p = hv * Cv;
        p = DPP_ADD(p, 0x111, 0xf);  // row_shr:1
        p = DPP_ADD(p, 0x112, 0xf);  // row_shr:2
        p = DPP_ADD(p, 0x114, 0xf);  // row_shr:4
        p = DPP_ADD(p, 0x118, 0xf);  // row_shr:8  -> lane15 of each row = row sum
        p = DPP_ADD(p, 0x142, 0xa);  // row_bcast:15 -> rows 1,3
        p = DPP_ADD(p, 0x143, 0xc);  // row_bcast:31 -> rows 2,3; lane63 = total

        // silu on all lanes (branchless), store from lane 63 only.
        const float sg = 1.0f / (1.0f + __expf(-zv));
        const float ov = p * (zv * sg);
        if (lane == 63) op[(size_t)t * (BB_ * D_)] = ov;

        xv = xn; zv = zn;
    }
}

extern "C" void kernel_launch(void* const* d_in, const int* in_sizes, int n_in,
                              void* d_out, int out_size, void* d_ws, size_t ws_size,
                              hipStream_t stream) {
    const float* x  = (const float*)d_in[0];   // [T,Bb,D]
    const float* z  = (const float*)d_in[1];   // [T,Bb,D]
    const float* h0 = (const float*)d_in[2];   // [Bb,D,S]
    const float* dl = (const float*)d_in[3];   // [D,S]
    const float* Bm = (const float*)d_in[4];   // [D,S]
    const float* C  = (const float*)d_in[5];   // [S]

    float* out = (float*)d_out;                            // [T,Bb,D]
    float* h   = (float*)d_out + (size_t)T_ * BB_ * D_;    // [T+1,Bb,D,S]

    const int waves  = BB_ * D_;           // 2048
    const int block  = 256;                // 4 waves
    const int grid   = waves * 64 / block; // 512

    hipLaunchKernelGGL(slot_elman_kernel, dim3(grid), dim3(block), 0, stream,
                       x, z, h0, dl, Bm, C, out, h);
}

// Round 4
// 146.990 us; speedup vs baseline: 2.8965x; 2.7649x over previous
//
#include <hip/hip_runtime.h>

// SlotElmanCell: T=1024, Bb=2, D=1024, S=64
//   decay = sigmoid(decay_logits)            [D,S]
//   h[t+1] = decay*h[t] + B*x[t]             [Bb,D,S]
//   out[t] = (h[t+1] . C) * silu(z[t])       [Bb,D]
// Outputs (concat flat): out [T,Bb,D] then h [T+1,Bb,D,S]  (f32)
//
// R4 = R3 with the writelane (unavailable builtin) replaced by
// v_cmp/v_cndmask select accumulate.
//  - Per 64-step block: ONE gather load per operand (lane l holds x[tb+l]),
//    double-buffered one block ahead -> load latency hidden under 64 steps.
//  - Per step: v_readlane (SGPR broadcast, no VMEM/DS) for x[t], silu(z[t]).
//  - silu(z) computed vectorized once per block (lane = t).
//  - out[t] accumulated into lane t of outacc via cndmask; ONE scatter
//    store per block (16 stores/wave instead of 1024 single-lane stores).

#define T_  1024
#define BB_ 2
#define D_  1024
#define S_  64
#define TB_ 64            // timestep block == wavefront size
#define NBLK_ (T_ / TB_)  // 16

// x + dpp_shifted(x); bound_ctrl=1 -> out-of-range sources read 0.
#define DPP_ADD(x, ctrl, rm) \
  ((x) + __int_as_float(__builtin_amdgcn_update_dpp( \
        0, __float_as_int(x), (ctrl), (rm), 0xf, true)))

__device__ __forceinline__ float readlane_f(float v, int lane) {
    return __int_as_float(__builtin_amdgcn_readlane(__float_as_int(v), lane));
}

__global__ __launch_bounds__(256, 2) void slot_elman_kernel(
    const float* __restrict__ x, const float* __restrict__ z,
    const float* __restrict__ h0, const float* __restrict__ dl,
    const float* __restrict__ Bm, const float* __restrict__ C,
    float* __restrict__ out, float* __restrict__ h)
{
    // Bijective XCD-aware block swizzle: 512 blocks, 8 XCDs, 64 blocks/XCD.
    // Same-XCD neighbor waves share the gather cache lines (16 d per 64B).
    const int nb  = gridDim.x;            // 512
    const int cpx = nb >> 3;              // 64
    const int bid = blockIdx.x;
    const int swz = (bid & 7) * cpx + (bid >> 3);

    const int wave = swz * (blockDim.x >> 6) + (threadIdx.x >> 6); // 0..2047
    const int lane = threadIdx.x & 63;                             // slot s
    const int b  = wave >> 10;            // D_=1024
    const int d  = wave & (D_ - 1);
    const int bd = b * D_ + d;
    const int ds = d * S_ + lane;

    // Per-lane constants
    const float decay = 1.0f / (1.0f + __expf(-dl[ds]));
    const float Bv    = Bm[ds];
    const float Cv    = C[lane];

    // Initial state + h[0] write
    float hv = h0[(size_t)bd * S_ + lane];
    h[(size_t)bd * S_ + lane] = hv;

    // Gather bases: lane l covers timestep tb+l (stride Bb*D between t)
    const float* xg_p = x + (size_t)lane * (BB_ * D_) + bd;
    const float* zg_p = z + (size_t)lane * (BB_ * D_) + bd;

    float*       hp = h + (size_t)(BB_ * D_ * S_) + (size_t)bd * S_ + lane;
    float*       op = out + (size_t)lane * (BB_ * D_) + bd;   // scatter base

    // Block 0 gathers
    float xgA = xg_p[0];
    float zgA = zg_p[0];

    for (int blk = 0; blk < NBLK_; ++blk) {
        const int tb = blk * TB_;

        // Prefetch next block's gathers (used 64 steps from now)
        const int tbn = (blk + 1 < NBLK_) ? (tb + TB_) : tb;
        const float xgB = xg_p[(size_t)tbn * (BB_ * D_)];
        const float zgB = zg_p[(size_t)tbn * (BB_ * D_)];

        // silu(z) for all 64 steps of this block, vectorized (lane = t)
        const float sgv = zgA * (1.0f / (1.0f + __expf(-zgA)));

        float outacc = 0.0f;

        #pragma unroll 8
        for (int i = 0; i < TB_; ++i) {
            // Broadcast x[tb+i] from lane i (SGPR, no VMEM/DS)
            const float xs = readlane_f(xgA, i);

            // Recurrence (only loop-carried dep: ~2 VALU ops)
            hv = fmaf(decay, hv, Bv * xs);

            // Coalesced h write: 64 lanes x 4B contiguous
            hp[(size_t)(tb + i) * (BB_ * D_ * S_)] = hv;

            // Wave-wide sum of hv*Cv via DPP (pure VALU)
            float p = hv * Cv;
            p = DPP_ADD(p, 0x111, 0xf);  // row_shr:1
            p = DPP_ADD(p, 0x112, 0xf);  // row_shr:2
            p = DPP_ADD(p, 0x114, 0xf);  // row_shr:4
            p = DPP_ADD(p, 0x118, 0xf);  // row_shr:8
            p = DPP_ADD(p, 0x142, 0xa);  // row_bcast:15 -> rows 1,3
            p = DPP_ADD(p, 0x143, 0xc);  // row_bcast:31 -> lane63 = total

            // out value: total(lane63) * silu(z[tb+i]); broadcast and
            // deposit into lane i of outacc via cndmask select.
            const float ov = p * readlane_f(sgv, i);   // lane63 holds result
            const float bc = readlane_f(ov, 63);       // SGPR broadcast
            outacc = (lane == i) ? bc : outacc;        // v_cmp + v_cndmask
        }

        // One scatter store per block: out[tb+lane][b][d]
        op[(size_t)tb * (BB_ * D_)] = outacc;

        xgA = xgB; zgA = zgB;
    }
}

extern "C" void kernel_launch(void* const* d_in, const int* in_sizes, int n_in,
                              void* d_out, int out_size, void* d_ws, size_t ws_size,
                              hipStream_t stream) {
    const float* x  = (const float*)d_in[0];   // [T,Bb,D]
    const float* z  = (const float*)d_in[1];   // [T,Bb,D]
    const float* h0 = (const float*)d_in[2];   // [Bb,D,S]
    const float* dl = (const float*)d_in[3];   // [D,S]
    const float* Bm = (const float*)d_in[4];   // [D,S]
    const float* C  = (const float*)d_in[5];   // [S]

    float* out = (float*)d_out;                            // [T,Bb,D]
    float* h   = (float*)d_out + (size_t)T_ * BB_ * D_;    // [T+1,Bb,D,S]

    const int waves  = BB_ * D_;           // 2048
    const int block  = 256;                // 4 waves
    const int grid   = waves * 64 / block; // 512

    hipLaunchKernelGGL(slot_elman_kernel, dim3(grid), dim3(block), 0, stream,
                       x, z, h0, dl, Bm, C, out, h);
}